// Round 1
// baseline (910.657 us; speedup 1.0000x reference)
//
#include <hip/hip_runtime.h>
#include <cstddef>

constexpr float GAMMA = 0.99f;
constexpr float GLAM  = 0.99f * 0.95f;   // gamma * gae_lambda
constexpr float ENT_C = 0.01f;

constexpr int T = 65536;
constexpr int O = 8;
constexpr int S = 1048576;
constexpr int A = 6;
constexpr int BLK = 256;
constexpr int SB = S / BLK;        // 4096 blocks per opponent
constexpr int CHUNK = T / BLK;     // 256 elements per thread in agent scan

// ws layout (floats):
//   ws[0..7]   : per-opponent ce sums (Σ logZ - tgt)
//   ws[8..15]  : per-opponent smooth-L1 sums
//   ws[16]     : agent loss partial (pl + 0.5*vl)

__global__ __launch_bounds__(BLK)
void fused_kernel(const float* __restrict__ arew,
                  const float* __restrict__ alp,
                  const float* __restrict__ aval,
                  const float* __restrict__ aent,
                  const float* __restrict__ olp,
                  const int*   __restrict__ oact,
                  const float* __restrict__ oval,
                  const float* __restrict__ orew,
                  float* __restrict__ ws)
{
    const int tid = threadIdx.x;

    if (blockIdx.x == 0) {
        // ----------------- agent loss: blocked reverse linear scan -----------------
        __shared__ float sR[BLK], sG[BLK];
        const int base = tid * CHUNK;

        // Phase 1: local recurrence with zero incoming carry -> c_block
        float cR = 0.f, cG = 0.f;
        for (int k = CHUNK - 1; k >= 0; --k) {
            int t = base + k;
            float r = arew[t];
            cR = GAMMA * cR + r;
            float delta = r + GAMMA * aval[t + 1] - aval[t];
            cG = GLAM * cG + delta;
        }
        sR[tid] = cR; sG[tid] = cG;
        __syncthreads();

        // Serial carry propagation across 256 chunks (reverse order), thread 0.
        if (tid == 0) {
            double aRd = 1.0, aGd = 1.0;
            for (int i = 0; i < CHUNK; ++i) { aRd *= 0.99; aGd *= 0.99 * 0.95; }
            const float aR = (float)aRd, aG = (float)aGd;
            float Rin = aval[T];   // R_T = values[-1]
            float Gin = 0.f;       // gae_T = 0
            for (int i = BLK - 1; i >= 0; --i) {
                float cr = sR[i], cg = sG[i];
                sR[i] = Rin; sG[i] = Gin;       // incoming carry for chunk i
                Rin = aR * Rin + cr;            // value at chunk start -> carry for chunk i-1
                Gin = aG * Gin + cg;
            }
        }
        __syncthreads();
        float R = sR[tid], g = sG[tid];
        __syncthreads();   // done reading carries; shared will be reused

        // Phase 2: exact sequential recurrence within chunk, accumulate pl/vl.
        float pl = 0.f, vl = 0.f;
        for (int k = CHUNK - 1; k >= 0; --k) {
            int t = base + k;
            float r = arew[t];
            R = GAMMA * R + r;
            float adv = R - aval[t];
            vl += 0.5f * adv * adv;
            float delta = r + GAMMA * aval[t + 1] - aval[t];
            g = GLAM * g + delta;
            pl += -alp[t] * g - ENT_C * aent[t];
        }
        sR[tid] = pl; sG[tid] = vl;
        __syncthreads();
        for (int stp = BLK / 2; stp > 0; stp >>= 1) {
            if (tid < stp) { sR[tid] += sR[tid + stp]; sG[tid] += sG[tid + stp]; }
            __syncthreads();
        }
        if (tid == 0) ws[16] = sR[0] + 0.5f * sG[0];   // pl + VALUE_LOSS_COEF * vl
        return;
    }

    // ----------------- opponent loss -----------------
    const int bid  = blockIdx.x - 1;
    const int o    = bid / SB;
    const int srel = (bid % SB) * BLK + tid;
    const size_t row = (size_t)o * S + srel;

    // 6 logits, 24B per row, 8B-aligned -> three float2 loads
    const float* lp = olp + row * (size_t)A;
    float2 p01 = *(const float2*)(lp);
    float2 p23 = *(const float2*)(lp + 2);
    float2 p45 = *(const float2*)(lp + 4);
    float l0 = p01.x, l1 = p01.y, l2 = p23.x, l3 = p23.y, l4 = p45.x, l5 = p45.y;

    float m  = fmaxf(fmaxf(fmaxf(l0, l1), fmaxf(l2, l3)), fmaxf(l4, l5));
    float se = __expf(l0 - m) + __expf(l1 - m) + __expf(l2 - m) +
               __expf(l3 - m) + __expf(l4 - m) + __expf(l5 - m);
    float logZ = m + __logf(se);
    int   a   = oact[row];
    float tgt = (a == 0) ? l0 : (a == 1) ? l1 : (a == 2) ? l2 :
                (a == 3) ? l3 : (a == 4) ? l4 : l5;
    float ce = logZ - tgt;

    float sl1 = 0.f;
    if (srel < S - 1) {
        float v0 = oval[row];
        float v1 = oval[row + 1];
        float rw = orew[(size_t)o * (S - 1) + srel];
        float d  = v0 - (rw + GAMMA * v1);
        float ad = fabsf(d);
        sl1 = (ad < 1.f) ? 0.5f * d * d : ad - 0.5f;
    }

    __shared__ float s1[BLK], s2[BLK];
    s1[tid] = ce; s2[tid] = sl1;
    __syncthreads();
    for (int stp = BLK / 2; stp > 0; stp >>= 1) {
        if (tid < stp) { s1[tid] += s1[tid + stp]; s2[tid] += s2[tid + stp]; }
        __syncthreads();
    }
    if (tid == 0) {
        atomicAdd(&ws[o],     s1[0]);
        atomicAdd(&ws[8 + o], s2[0]);
    }
}

__global__ void finalize_kernel(const float* __restrict__ ws,
                                const float* __restrict__ coefs,
                                float* __restrict__ out)
{
    if (threadIdx.x == 0 && blockIdx.x == 0) {
        float tot = ws[16];                       // agent loss
        for (int o = 0; o < O; ++o)
            tot += coefs[o] * (ws[o] / (float)S + ws[8 + o] / (float)(S - 1));
        out[0] = tot;
    }
}

extern "C" void kernel_launch(void* const* d_in, const int* in_sizes, int n_in,
                              void* d_out, int out_size, void* d_ws, size_t ws_size,
                              hipStream_t stream)
{
    const float* arew  = (const float*)d_in[0];
    const float* alp   = (const float*)d_in[1];
    const float* aval  = (const float*)d_in[2];
    const float* aent  = (const float*)d_in[3];
    const float* olp   = (const float*)d_in[4];
    const int*   oact  = (const int*)  d_in[5];
    const float* oval  = (const float*)d_in[6];
    const float* orew  = (const float*)d_in[7];
    const float* ocoef = (const float*)d_in[8];
    float* ws = (float*)d_ws;

    hipMemsetAsync(ws, 0, 32 * sizeof(float), stream);   // zero accumulators every call
    fused_kernel<<<1 + O * SB, BLK, 0, stream>>>(arew, alp, aval, aent,
                                                 olp, oact, oval, orew, ws);
    finalize_kernel<<<1, 64, 0, stream>>>(ws, ocoef, (float*)d_out);
}

// Round 2
// 107.704 us; speedup vs baseline: 8.4552x; 8.4552x over previous
//
#include <hip/hip_runtime.h>
#include <cstddef>

constexpr float GAMMA = 0.99f;
constexpr float GLAM  = 0.99f * 0.95f;   // gamma * gae_lambda
constexpr float ENT_C = 0.01f;

constexpr int T = 65536;
constexpr int O = 8;
constexpr int S = 1048576;
constexpr int A = 6;
constexpr int BLK = 256;

constexpr int BPO        = 512;            // opponent blocks per o
constexpr int OPP_BLOCKS = O * BPO;        // 4096
constexpr int ROWS_PER_B = S / BPO;        // 2048 rows per block
constexpr int ROWS_PER_T = ROWS_PER_B / BLK; // 8 rows per thread (2 iters x 4)
constexpr int CHUNK = T / BLK;             // 256 elements per thread in agent scan

// ws layout (floats):
//   ws[0      .. 4095] : per-block ce partials      (block b -> ws[b])
//   ws[4096   .. 8191] : per-block smooth-L1 partials
//   ws[8192]           : agent loss
// No atomics anywhere; every slot is written unconditionally each call.

__global__ __launch_bounds__(BLK)
void fused_kernel(const float* __restrict__ arew,
                  const float* __restrict__ alp,
                  const float* __restrict__ aval,
                  const float* __restrict__ aent,
                  const float* __restrict__ olp,
                  const int*   __restrict__ oact,
                  const float* __restrict__ oval,
                  const float* __restrict__ orew,
                  float* __restrict__ ws)
{
    const int tid = threadIdx.x;

    if (blockIdx.x == 0) {
        // ----------------- agent loss: blocked reverse linear scan -----------------
        __shared__ float sR[BLK], sG[BLK];
        const int base = tid * CHUNK;

        // Phase 1: local recurrence with zero incoming carry (float4-vectorized).
        float cR = 0.f, cG = 0.f;
        float nextv = aval[base + CHUNK];          // aval[t+1] for the top element
        #pragma unroll 4
        for (int k4 = CHUNK - 4; k4 >= 0; k4 -= 4) {
            float4 r4 = *reinterpret_cast<const float4*>(&arew[base + k4]);
            float4 v4 = *reinterpret_cast<const float4*>(&aval[base + k4]);
            cR = GAMMA * cR + r4.w;  cG = GLAM * cG + (r4.w + GAMMA * nextv - v4.w);
            cR = GAMMA * cR + r4.z;  cG = GLAM * cG + (r4.z + GAMMA * v4.w  - v4.z);
            cR = GAMMA * cR + r4.y;  cG = GLAM * cG + (r4.y + GAMMA * v4.z  - v4.y);
            cR = GAMMA * cR + r4.x;  cG = GLAM * cG + (r4.x + GAMMA * v4.y  - v4.x);
            nextv = v4.x;
        }
        sR[tid] = cR; sG[tid] = cG;
        __syncthreads();

        // Serial carry propagation across 256 chunks (reverse order), thread 0.
        if (tid == 0) {
            double aRd = 1.0, aGd = 1.0;
            for (int i = 0; i < CHUNK; ++i) { aRd *= 0.99; aGd *= 0.99 * 0.95; }
            const float aR = (float)aRd, aG = (float)aGd;
            float Rin = aval[T];   // R_T = values[-1]
            float Gin = 0.f;       // gae_T = 0
            for (int i = BLK - 1; i >= 0; --i) {
                float cr = sR[i], cg = sG[i];
                sR[i] = Rin; sG[i] = Gin;
                Rin = aR * Rin + cr;
                Gin = aG * Gin + cg;
            }
        }
        __syncthreads();
        float R = sR[tid], g = sG[tid];
        __syncthreads();

        // Phase 2: exact sequential recurrence with correct carries (vectorized).
        float pl = 0.f, vl = 0.f;
        nextv = aval[base + CHUNK];
        #pragma unroll 4
        for (int k4 = CHUNK - 4; k4 >= 0; k4 -= 4) {
            float4 r4 = *reinterpret_cast<const float4*>(&arew[base + k4]);
            float4 v4 = *reinterpret_cast<const float4*>(&aval[base + k4]);
            float4 l4 = *reinterpret_cast<const float4*>(&alp [base + k4]);
            float4 e4 = *reinterpret_cast<const float4*>(&aent[base + k4]);

            R = GAMMA * R + r4.w; { float adv = R - v4.w; vl += 0.5f * adv * adv; }
            g = GLAM * g + (r4.w + GAMMA * nextv - v4.w); pl += -l4.w * g - ENT_C * e4.w;
            R = GAMMA * R + r4.z; { float adv = R - v4.z; vl += 0.5f * adv * adv; }
            g = GLAM * g + (r4.z + GAMMA * v4.w  - v4.z); pl += -l4.z * g - ENT_C * e4.z;
            R = GAMMA * R + r4.y; { float adv = R - v4.y; vl += 0.5f * adv * adv; }
            g = GLAM * g + (r4.y + GAMMA * v4.z  - v4.y); pl += -l4.y * g - ENT_C * e4.y;
            R = GAMMA * R + r4.x; { float adv = R - v4.x; vl += 0.5f * adv * adv; }
            g = GLAM * g + (r4.x + GAMMA * v4.y  - v4.x); pl += -l4.x * g - ENT_C * e4.x;
            nextv = v4.x;
        }
        sR[tid] = pl; sG[tid] = vl;
        __syncthreads();
        for (int stp = BLK / 2; stp > 0; stp >>= 1) {
            if (tid < stp) { sR[tid] += sR[tid + stp]; sG[tid] += sG[tid + stp]; }
            __syncthreads();
        }
        if (tid == 0) ws[2 * OPP_BLOCKS] = sR[0] + 0.5f * sG[0];
        return;
    }

    // ----------------- opponent loss: 8 rows/thread, vectorized -----------------
    const int bid = blockIdx.x - 1;
    const int o   = bid / BPO;
    const int seg = bid % BPO;
    const int row0 = seg * ROWS_PER_B;

    float ce_acc = 0.f, sl_acc = 0.f;

    #pragma unroll
    for (int it = 0; it < ROWS_PER_T / 4; ++it) {
        const int srel = row0 + it * (BLK * 4) + tid * 4;      // first of 4 rows
        const size_t gr = (size_t)o * S + srel;

        // --- cross-entropy on 4 rows: 24 consecutive floats = 6 float4 ---
        const float* lp = olp + gr * (size_t)A;
        float4 q0 = reinterpret_cast<const float4*>(lp)[0];
        float4 q1 = reinterpret_cast<const float4*>(lp)[1];
        float4 q2 = reinterpret_cast<const float4*>(lp)[2];
        float4 q3 = reinterpret_cast<const float4*>(lp)[3];
        float4 q4 = reinterpret_cast<const float4*>(lp)[4];
        float4 q5 = reinterpret_cast<const float4*>(lp)[5];
        int4 act = *reinterpret_cast<const int4*>(&oact[gr]);

        float lg[24] = { q0.x,q0.y,q0.z,q0.w, q1.x,q1.y,q1.z,q1.w,
                         q2.x,q2.y,q2.z,q2.w, q3.x,q3.y,q3.z,q3.w,
                         q4.x,q4.y,q4.z,q4.w, q5.x,q5.y,q5.z,q5.w };
        int ac[4] = { act.x, act.y, act.z, act.w };
        #pragma unroll
        for (int j = 0; j < 4; ++j) {
            const float* l = &lg[6 * j];
            float m = fmaxf(fmaxf(fmaxf(l[0], l[1]), fmaxf(l[2], l[3])), fmaxf(l[4], l[5]));
            float se = __expf(l[0]-m) + __expf(l[1]-m) + __expf(l[2]-m)
                     + __expf(l[3]-m) + __expf(l[4]-m) + __expf(l[5]-m);
            ce_acc += (m + __logf(se)) - l[ac[j]];
        }

        // --- smooth-L1 on 4 rows ---
        float4 v4 = *reinterpret_cast<const float4*>(&oval[gr]);
        float v[5] = { v4.x, v4.y, v4.z, v4.w,
                       (srel + 4 <= S - 1) ? oval[gr + 4] : 0.f };
        const size_t rr = (size_t)o * (S - 1) + srel;
        #pragma unroll
        for (int j = 0; j < 4; ++j) {
            if (srel + j < S - 1) {
                float rw = orew[rr + j];
                float d  = v[j] - (rw + GAMMA * v[j + 1]);
                float ad = fabsf(d);
                sl_acc += (ad < 1.f) ? 0.5f * d * d : ad - 0.5f;
            }
        }
    }

    __shared__ float s1[BLK], s2[BLK];
    s1[tid] = ce_acc; s2[tid] = sl_acc;
    __syncthreads();
    for (int stp = BLK / 2; stp > 0; stp >>= 1) {
        if (tid < stp) { s1[tid] += s1[tid + stp]; s2[tid] += s2[tid + stp]; }
        __syncthreads();
    }
    if (tid == 0) {
        ws[bid]              = s1[0];   // private slot: plain store, no atomic
        ws[OPP_BLOCKS + bid] = s2[0];
    }
}

__global__ __launch_bounds__(BLK)
void finalize_kernel(const float* __restrict__ ws,
                     const float* __restrict__ coefs,
                     float* __restrict__ out)
{
    const int tid = threadIdx.x;
    __shared__ float r1[BLK], r2[BLK];
    float tot = 0.f;
    for (int o = 0; o < O; ++o) {
        const float* cw = ws + o * BPO;
        const float* sw = ws + OPP_BLOCKS + o * BPO;
        r1[tid] = cw[tid] + cw[tid + BLK];
        r2[tid] = sw[tid] + sw[tid + BLK];
        __syncthreads();
        for (int stp = BLK / 2; stp > 0; stp >>= 1) {
            if (tid < stp) { r1[tid] += r1[tid + stp]; r2[tid] += r2[tid + stp]; }
            __syncthreads();
        }
        if (tid == 0)
            tot += coefs[o] * (r1[0] / (float)S + r2[0] / (float)(S - 1));
        __syncthreads();
    }
    if (tid == 0) out[0] = tot + ws[2 * OPP_BLOCKS];
}

extern "C" void kernel_launch(void* const* d_in, const int* in_sizes, int n_in,
                              void* d_out, int out_size, void* d_ws, size_t ws_size,
                              hipStream_t stream)
{
    const float* arew  = (const float*)d_in[0];
    const float* alp   = (const float*)d_in[1];
    const float* aval  = (const float*)d_in[2];
    const float* aent  = (const float*)d_in[3];
    const float* olp   = (const float*)d_in[4];
    const int*   oact  = (const int*)  d_in[5];
    const float* oval  = (const float*)d_in[6];
    const float* orew  = (const float*)d_in[7];
    const float* ocoef = (const float*)d_in[8];
    float* ws = (float*)d_ws;

    fused_kernel<<<1 + OPP_BLOCKS, BLK, 0, stream>>>(arew, alp, aval, aent,
                                                     olp, oact, oval, orew, ws);
    finalize_kernel<<<1, BLK, 0, stream>>>(ws, ocoef, (float*)d_out);
}

// Round 3
// 100.817 us; speedup vs baseline: 9.0327x; 1.0683x over previous
//
#include <hip/hip_runtime.h>
#include <cstddef>

constexpr float GAMMA = 0.99f;
constexpr float GLAM  = 0.99f * 0.95f;   // gamma * gae_lambda
constexpr float ENT_C = 0.01f;

constexpr int T = 65536;
constexpr int O = 8;
constexpr int S = 1048576;
constexpr int A = 6;
constexpr int BLK = 256;

constexpr int BPO        = 512;              // opponent blocks per o
constexpr int OPP_BLOCKS = O * BPO;          // 4096
constexpr int ROWS_PER_B = S / BPO;          // 2048 rows per block
constexpr int STAGE_ROWS = 512;              // rows staged per LDS pass
constexpr int NSTAGE     = ROWS_PER_B / STAGE_ROWS;   // 4
constexpr int CHUNK      = T / BLK;          // 256 elements per thread in agent scan

// ws layout (floats):
//   ws[0      .. 4095] : per-block ce partials
//   ws[4096   .. 8191] : per-block smooth-L1 partials
//   ws[8192]           : agent loss

__device__ __forceinline__ float row_ce(float l0, float l1, float l2,
                                        float l3, float l4, float l5, int a)
{
    float m  = fmaxf(fmaxf(fmaxf(l0, l1), fmaxf(l2, l3)), fmaxf(l4, l5));
    float se = __expf(l0 - m) + __expf(l1 - m) + __expf(l2 - m) +
               __expf(l3 - m) + __expf(l4 - m) + __expf(l5 - m);
    float tgt = (a == 0) ? l0 : (a == 1) ? l1 : (a == 2) ? l2 :
                (a == 3) ? l3 : (a == 4) ? l4 : l5;
    return (m + __logf(se)) - tgt;
}

__global__ __launch_bounds__(BLK)
void fused_kernel(const float* __restrict__ arew,
                  const float* __restrict__ alp,
                  const float* __restrict__ aval,
                  const float* __restrict__ aent,
                  const float* __restrict__ olp,
                  const int*   __restrict__ oact,
                  const float* __restrict__ oval,
                  const float* __restrict__ orew,
                  float* __restrict__ ws)
{
    const int tid = threadIdx.x;
    __shared__ float s1[BLK], s2[BLK];

    if (blockIdx.x == 0) {
        // ----------------- agent loss: blocked reverse linear scan -----------------
        const int base = tid * CHUNK;

        // Phase 1: local recurrence with zero incoming carry (float4-vectorized).
        float cR = 0.f, cG = 0.f;
        float nextv = aval[base + CHUNK];
        #pragma unroll 4
        for (int k4 = CHUNK - 4; k4 >= 0; k4 -= 4) {
            float4 r4 = *reinterpret_cast<const float4*>(&arew[base + k4]);
            float4 v4 = *reinterpret_cast<const float4*>(&aval[base + k4]);
            cR = GAMMA * cR + r4.w;  cG = GLAM * cG + (r4.w + GAMMA * nextv - v4.w);
            cR = GAMMA * cR + r4.z;  cG = GLAM * cG + (r4.z + GAMMA * v4.w  - v4.z);
            cR = GAMMA * cR + r4.y;  cG = GLAM * cG + (r4.y + GAMMA * v4.z  - v4.y);
            cR = GAMMA * cR + r4.x;  cG = GLAM * cG + (r4.x + GAMMA * v4.y  - v4.x);
            nextv = v4.x;
        }
        s1[tid] = cR; s2[tid] = cG;
        __syncthreads();

        // Serial carry propagation across 256 chunks (reverse), thread 0.
        if (tid == 0) {
            double aRd = 1.0, aGd = 1.0;
            for (int i = 0; i < CHUNK; ++i) { aRd *= 0.99; aGd *= 0.99 * 0.95; }
            const float aR = (float)aRd, aG = (float)aGd;
            float Rin = aval[T];
            float Gin = 0.f;
            for (int i = BLK - 1; i >= 0; --i) {
                float cr = s1[i], cg = s2[i];
                s1[i] = Rin; s2[i] = Gin;
                Rin = aR * Rin + cr;
                Gin = aG * Gin + cg;
            }
        }
        __syncthreads();
        float R = s1[tid], g = s2[tid];
        __syncthreads();

        // Phase 2: exact sequential recurrence with correct carries.
        float pl = 0.f, vl = 0.f;
        nextv = aval[base + CHUNK];
        #pragma unroll 4
        for (int k4 = CHUNK - 4; k4 >= 0; k4 -= 4) {
            float4 r4 = *reinterpret_cast<const float4*>(&arew[base + k4]);
            float4 v4 = *reinterpret_cast<const float4*>(&aval[base + k4]);
            float4 l4 = *reinterpret_cast<const float4*>(&alp [base + k4]);
            float4 e4 = *reinterpret_cast<const float4*>(&aent[base + k4]);

            R = GAMMA * R + r4.w; { float adv = R - v4.w; vl += 0.5f * adv * adv; }
            g = GLAM * g + (r4.w + GAMMA * nextv - v4.w); pl += -l4.w * g - ENT_C * e4.w;
            R = GAMMA * R + r4.z; { float adv = R - v4.z; vl += 0.5f * adv * adv; }
            g = GLAM * g + (r4.z + GAMMA * v4.w  - v4.z); pl += -l4.z * g - ENT_C * e4.z;
            R = GAMMA * R + r4.y; { float adv = R - v4.y; vl += 0.5f * adv * adv; }
            g = GLAM * g + (r4.y + GAMMA * v4.z  - v4.y); pl += -l4.y * g - ENT_C * e4.y;
            R = GAMMA * R + r4.x; { float adv = R - v4.x; vl += 0.5f * adv * adv; }
            g = GLAM * g + (r4.x + GAMMA * v4.y  - v4.x); pl += -l4.x * g - ENT_C * e4.x;
            nextv = v4.x;
        }
        s1[tid] = pl; s2[tid] = vl;
        __syncthreads();
        for (int stp = BLK / 2; stp > 0; stp >>= 1) {
            if (tid < stp) { s1[tid] += s1[tid + stp]; s2[tid] += s2[tid + stp]; }
            __syncthreads();
        }
        if (tid == 0) ws[2 * OPP_BLOCKS] = s1[0] + 0.5f * s2[0];
        return;
    }

    // ----------------- opponent loss: LDS-coalesced logits, 2 rows/thread/stage ---
    __shared__ float lds[STAGE_ROWS * A];    // 12288 B

    const int bid  = blockIdx.x - 1;
    const int o    = bid / BPO;
    const int seg  = bid % BPO;
    const int row0 = seg * ROWS_PER_B;
    const size_t obase = (size_t)o * S;
    const size_t rbase = (size_t)o * (S - 1);

    // prefetch registers (T14: issue early, consume late)
    float4 pa, pb, pc; int2 pact; float2 pv; float pv2, pr0, pr1;

    auto issue = [&](int s) {
        const int srow = row0 + s * STAGE_ROWS;
        const float4* lp4 = reinterpret_cast<const float4*>(olp + (obase + srow) * (size_t)A);
        pa = lp4[tid];
        pb = lp4[tid + BLK];
        pc = lp4[tid + 2 * BLK];
        const int r = srow + 2 * tid;                 // this thread's first row
        const size_t gr = obase + r;
        pact = *reinterpret_cast<const int2*>(&oact[gr]);
        pv   = *reinterpret_cast<const float2*>(&oval[gr]);
        pv2  = (r + 2 <= S - 1) ? oval[gr + 2] : 0.f;
        pr0  = orew[rbase + r];                       // r <= S-2 always
        pr1  = (r + 1 < S - 1) ? orew[rbase + r + 1] : 0.f;
    };

    float ce_acc = 0.f, sl_acc = 0.f;
    issue(0);

    #pragma unroll
    for (int s = 0; s < NSTAGE; ++s) {
        __syncthreads();                               // previous stage's LDS reads done
        reinterpret_cast<float4*>(lds)[tid]           = pa;
        reinterpret_cast<float4*>(lds)[tid + BLK]     = pb;
        reinterpret_cast<float4*>(lds)[tid + 2 * BLK] = pc;
        const int2  act = pact;
        const float2 v  = pv;
        const float v2 = pv2, rw0 = pr0, rw1 = pr1;
        const int r = row0 + s * STAGE_ROWS + 2 * tid;
        if (s + 1 < NSTAGE) issue(s + 1);              // overlap next-stage HBM latency
        __syncthreads();                               // staged logits visible

        // 2 rows from LDS: 48 B at dword-stride 12 -> conflict-free b128 reads
        const float* lrow = &lds[12 * tid];
        float4 q0 = *reinterpret_cast<const float4*>(lrow);
        float4 q1 = *reinterpret_cast<const float4*>(lrow + 4);
        float4 q2 = *reinterpret_cast<const float4*>(lrow + 8);

        ce_acc += row_ce(q0.x, q0.y, q0.z, q0.w, q1.x, q1.y, act.x);
        ce_acc += row_ce(q1.z, q1.w, q2.x, q2.y, q2.z, q2.w, act.y);

        {   // smooth-L1, row r (always r < S-1)
            float d  = v.x - (rw0 + GAMMA * v.y);
            float ad = fabsf(d);
            sl_acc += (ad < 1.f) ? 0.5f * d * d : ad - 0.5f;
        }
        if (r + 1 < S - 1) {   // smooth-L1, row r+1
            float d  = v.y - (rw1 + GAMMA * v2);
            float ad = fabsf(d);
            sl_acc += (ad < 1.f) ? 0.5f * d * d : ad - 0.5f;
        }
    }

    s1[tid] = ce_acc; s2[tid] = sl_acc;
    __syncthreads();
    for (int stp = BLK / 2; stp > 0; stp >>= 1) {
        if (tid < stp) { s1[tid] += s1[tid + stp]; s2[tid] += s2[tid + stp]; }
        __syncthreads();
    }
    if (tid == 0) {
        ws[bid]              = s1[0];
        ws[OPP_BLOCKS + bid] = s2[0];
    }
}

__global__ __launch_bounds__(BLK)
void finalize_kernel(const float* __restrict__ ws,
                     const float* __restrict__ coefs,
                     float* __restrict__ out)
{
    const int tid = threadIdx.x;
    __shared__ float r1[BLK], r2[BLK];
    float tot = 0.f;
    for (int o = 0; o < O; ++o) {
        const float* cw = ws + o * (BPO);
        const float* sw = ws + OPP_BLOCKS + o * BPO;
        r1[tid] = cw[tid] + cw[tid + BLK];
        r2[tid] = sw[tid] + sw[tid + BLK];
        __syncthreads();
        for (int stp = BLK / 2; stp > 0; stp >>= 1) {
            if (tid < stp) { r1[tid] += r1[tid + stp]; r2[tid] += r2[tid + stp]; }
            __syncthreads();
        }
        if (tid == 0)
            tot += coefs[o] * (r1[0] / (float)S + r2[0] / (float)(S - 1));
        __syncthreads();
    }
    if (tid == 0) out[0] = tot + ws[2 * OPP_BLOCKS];
}

extern "C" void kernel_launch(void* const* d_in, const int* in_sizes, int n_in,
                              void* d_out, int out_size, void* d_ws, size_t ws_size,
                              hipStream_t stream)
{
    const float* arew  = (const float*)d_in[0];
    const float* alp   = (const float*)d_in[1];
    const float* aval  = (const float*)d_in[2];
    const float* aent  = (const float*)d_in[3];
    const float* olp   = (const float*)d_in[4];
    const int*   oact  = (const int*)  d_in[5];
    const float* oval  = (const float*)d_in[6];
    const float* orew  = (const float*)d_in[7];
    const float* ocoef = (const float*)d_in[8];
    float* ws = (float*)d_ws;

    fused_kernel<<<1 + OPP_BLOCKS, BLK, 0, stream>>>(arew, alp, aval, aent,
                                                     olp, oact, oval, orew, ws);
    finalize_kernel<<<1, BLK, 0, stream>>>(ws, ocoef, (float*)d_out);
}